// Round 5
// baseline (218.733 us; speedup 1.0000x reference)
//
#include <hip/hip_runtime.h>
#include <hip/hip_bf16.h>
#include <stdint.h>

#define KDIM 512
#define OUT_F 512
#define BN 128           // output cols per block (one nt slab)
#define MROWS 32         // rows per mtile step
#define MT_PER_BLK 8     // mtiles per persistent block
#define NTHREADS 256     // 4 waves

typedef __attribute__((ext_vector_type(8))) short short8;
typedef __attribute__((ext_vector_type(4))) float floatx4;

__device__ __forceinline__ ushort f2bf(float f) {
  uint32_t u = __builtin_bit_cast(uint32_t, f);
  uint32_t r = u + 0x7fffu + ((u >> 16) & 1u);   // RNE bf16
  return (ushort)(r >> 16);
}

typedef const __attribute__((address_space(1))) uint32_t* gas1_u32;
typedef __attribute__((address_space(3))) uint32_t* gas3_u32;

__device__ __forceinline__ void gload_lds16(const void* g, void* l) {
  __builtin_amdgcn_global_load_lds((gas1_u32)g, (gas3_u32)l, 16, 0, 0);
}

// ---------------------------------------------------------------------------
// Prep: W_eff (512x512) bf16 as 4 slabs [nt][128][512], XOR-pre-swizzled so
// the GEMM can stage linearly with global_load_lds and read swizzled.
// ---------------------------------------------------------------------------
__global__ void quat_prep_kernel(const float* __restrict__ wr, const float* __restrict__ wi,
                                 const float* __restrict__ wj, const float* __restrict__ wk,
                                 ushort* __restrict__ Bimg) {
  int idx = blockIdx.x * 256 + threadIdx.x;
  if (idx >= 512 * 512) return;
  int n = idx >> 9;        // output-feature index O
  int k = idx & 511;       // input-feature index C
  int og = n >> 7, o = n & 127, cg = k >> 7, c = k & 127;
  static const int   blkT[16] = {0,1,2,3, 1,0,3,2, 2,3,0,1, 3,2,1,0};
  static const float sgnT[16] = {1.f,-1.f,-1.f,-1.f, 1.f,1.f,1.f,-1.f,
                                 1.f,-1.f,1.f,1.f,   1.f,1.f,-1.f,1.f};
  int sel = og * 4 + cg;
  const float* Ws;
  switch (blkT[sel]) {
    case 0: Ws = wr; break;
    case 1: Ws = wi; break;
    case 2: Ws = wj; break;
    default: Ws = wk; break;
  }
  float v = sgnT[sel] * Ws[o * 128 + c];
  int nt = n >> 7, nl = n & 127;
  int dst = nt * (BN * KDIM) + nl * KDIM + (k ^ ((nl & 7) << 3));
  Bimg[dst] = f2bf(v);
}

// ---------------------------------------------------------------------------
// GEMM: out[M,512] = X[M,512] * W_eff^T (+bias)
// Persistent block: B slab (128KB) staged once; loop 8 mtiles of 32 rows.
// A fetched ROW-LINEAR (contiguous 64KB burst) into registers, pinned with
// sched_barrier so loads stay in flight across the whole compute phase,
// then converted to bf16 into a 32KB LDS tile. LDS total = 160KB (1 blk/CU).
// ---------------------------------------------------------------------------
__global__ void __launch_bounds__(NTHREADS, 1)
quat_gemm_kernel(const float* __restrict__ X, const ushort* __restrict__ Bimg,
                 const float* __restrict__ bias, float* __restrict__ Out) {
  __shared__ __align__(16) ushort Bs[BN * KDIM];     // 128 KB
  __shared__ __align__(16) ushort As[MROWS * KDIM];  // 32 KB

  int bid = blockIdx.x;
  int x = bid & 7;                      // XCD (hw: bid % 8)
  int j = bid >> 3;                     // [0,256)
  int nt = j & 3;                       // 4 nt-siblings share x -> same XCD L2
  int g = j >> 2;                       // [0,64)
  int strip = x + 8 * g;                // [0,512)
  size_t row0 = (size_t)strip * (MT_PER_BLK * MROWS);   // strip*256

  int tid = threadIdx.x, lane = tid & 63, wid = tid >> 6;   // wid = wn in [0,4)
  const int lrow = lane & 15;
  const int lg   = lane >> 4;

  const float4* X4 = (const float4*)X;
  float4 buf[16];                       // 64 VGPR row-linear A burst

  auto issueA = [&](int t) {            // 64KB contiguous: rows row0+t*32 .. +32
    size_t base4 = (row0 + (size_t)t * MROWS) * (KDIM / 4);
#pragma unroll
    for (int i = 0; i < 16; ++i)
      buf[i] = X4[base4 + i * 256 + tid];
  };

  auto writeA = [&]() {                 // cvt fp32->bf16, swizzled ds_write
#pragma unroll
    for (int i = 0; i < 16; ++i) {
      int flat = i * 1024 + tid * 4;    // float index within 32x512 tile
      int row = flat >> 9;
      int col = flat & 511;
      ushort4 o4;
      o4.x = f2bf(buf[i].x); o4.y = f2bf(buf[i].y);
      o4.z = f2bf(buf[i].z); o4.w = f2bf(buf[i].w);
      *reinterpret_cast<ushort4*>(As + row * KDIM + (col ^ ((row & 7) << 3))) = o4;
    }
  };

  // ---- prologue: A(0) burst + B slab stage, then materialize A(0) ----
  issueA(0);
  {
    const ushort* src = Bimg + nt * (BN * KDIM) + wid * 16384 + lane * 8;
    ushort* dst = Bs + wid * 16384;     // per wave: 32 chunks x 512 ushorts
#pragma unroll
    for (int i = 0; i < 32; ++i)
      gload_lds16(src + i * 512, dst + i * 512);
  }
  writeA();                             // waits A(0) vmcnt; B gloads still queued
  __syncthreads();                      // drains all; B + A(0) visible

  const float* bb = bias + nt * BN;
  float bv[2];
#pragma unroll
  for (int n = 0; n < 2; ++n) bv[n] = bb[wid * 32 + n * 16 + lrow];

  // B fragment rows are fixed across mtiles: precompute offsets
  int boff[2];
#pragma unroll
  for (int n = 0; n < 2; ++n) {
    int row = wid * 32 + n * 16 + lrow;
    boff[n] = row * KDIM;
  }
  int aoff[2], asw[2], bsw[2];
#pragma unroll
  for (int m = 0; m < 2; ++m) {
    int row = m * 16 + lrow;
    aoff[m] = row * KDIM;
    asw[m] = (row & 7) << 3;
    bsw[m] = (((wid * 32 + m * 16 + lrow) & 7) << 3);
  }

#pragma unroll 1
  for (int t = 0; t < MT_PER_BLK; ++t) {
    if (t < MT_PER_BLK - 1) {
      issueA(t + 1);                    // row-linear burst for next mtile
      __builtin_amdgcn_sched_barrier(0);// pin: loads stay issued HERE
    }

    floatx4 acc[2][2];
#pragma unroll
    for (int m = 0; m < 2; ++m)
#pragma unroll
      for (int n = 0; n < 2; ++n) acc[m][n] = {0.f, 0.f, 0.f, 0.f};

#pragma unroll
    for (int kt = 0; kt < 16; ++kt) {
      int kb = kt * 32 + lg * 8;
      short8 af[2], bfv[2];
#pragma unroll
      for (int m = 0; m < 2; ++m)
        af[m] = *reinterpret_cast<const short8*>(As + aoff[m] + (kb ^ asw[m]));
#pragma unroll
      for (int n = 0; n < 2; ++n)
        bfv[n] = *reinterpret_cast<const short8*>(Bs + boff[n] + (kb ^ bsw[n]));
#pragma unroll
      for (int m = 0; m < 2; ++m)
#pragma unroll
        for (int n = 0; n < 2; ++n)
          acc[m][n] = __builtin_amdgcn_mfma_f32_16x16x32_bf16(af[m], bfv[n], acc[m][n], 0, 0, 0);
    }

    // store this mtile's 32x128 fp32 tile
    {
      size_t r0 = row0 + (size_t)t * MROWS;
      float* Ob = Out + r0 * OUT_F + nt * BN;
#pragma unroll
      for (int n = 0; n < 2; ++n) {
        int col = wid * 32 + n * 16 + lrow;
#pragma unroll
        for (int m = 0; m < 2; ++m) {
          int rr = m * 16 + lg * 4;
#pragma unroll
          for (int jj = 0; jj < 4; ++jj)
            Ob[(size_t)(rr + jj) * OUT_F + col] = acc[m][n][jj] + bv[n];
        }
      }
    }

    if (t < MT_PER_BLK - 1) {
      __syncthreads();                  // all waves done reading As(t)
      writeA();                         // vmcnt-waits burst, cvt, ds_write
      __syncthreads();                  // As(t+1) visible
    }
  }
}

extern "C" void kernel_launch(void* const* d_in, const int* in_sizes, int n_in,
                              void* d_out, int out_size, void* d_ws, size_t ws_size,
                              hipStream_t stream) {
  const float* x    = (const float*)d_in[0];
  const float* wr   = (const float*)d_in[1];
  const float* wi   = (const float*)d_in[2];
  const float* wj   = (const float*)d_in[3];
  const float* wk   = (const float*)d_in[4];
  const float* bias = (const float*)d_in[5];
  float* out = (float*)d_out;
  ushort* Bimg = (ushort*)d_ws;         // 512 KB

  int M = in_sizes[0] / KDIM;           // 131072
  int nwg = (M / (MROWS * MT_PER_BLK)) * 4;   // 512 strips * 4 nt = 2048

  hipLaunchKernelGGL(quat_prep_kernel, dim3((512 * 512 + 255) / 256), dim3(256), 0, stream,
                     wr, wi, wj, wk, Bimg);
  hipLaunchKernelGGL(quat_gemm_kernel, dim3(nwg), dim3(NTHREADS), 0, stream,
                     x, Bimg, bias, out);
}

// Round 6
// 163.801 us; speedup vs baseline: 1.3354x; 1.3354x over previous
//
#include <hip/hip_runtime.h>
#include <hip/hip_bf16.h>
#include <stdint.h>

#define KDIM 512
#define OUT_F 512
#define BM 64            // rows per block
#define BK 32            // k per step
#define NSTEP 16         // KDIM / BK
#define NTHREADS 512     // 8 waves, 2M x 4N

typedef __attribute__((ext_vector_type(8))) short short8;
typedef __attribute__((ext_vector_type(4))) float floatx4;

__device__ __forceinline__ ushort f2bf(float f) {
  uint32_t u = __builtin_bit_cast(uint32_t, f);
  uint32_t r = u + 0x7fffu + ((u >> 16) & 1u);   // RNE bf16
  return (ushort)(r >> 16);
}

typedef const __attribute__((address_space(1))) uint32_t* gas1_u32;
typedef __attribute__((address_space(3))) uint32_t* gas3_u32;

__device__ __forceinline__ void gload_lds16(const void* g, void* l) {
  // per-lane global src; LDS dest = wave-uniform base + lane*16 bytes
  __builtin_amdgcn_global_load_lds((gas1_u32)g, (gas3_u32)l, 16, 0, 0);
}

// ---------------------------------------------------------------------------
// Prep: W_eff (512x512) bf16, laid out as [kt(16)][o(512)][k(32)] with the
// XOR swizzle baked in, so the GEMM stages each 32KB kt-slab linearly via
// global_load_lds and reads swizzled.
// ---------------------------------------------------------------------------
__global__ void quat_prep_kernel(const float* __restrict__ wr, const float* __restrict__ wi,
                                 const float* __restrict__ wj, const float* __restrict__ wk,
                                 ushort* __restrict__ Bimg) {
  int idx = blockIdx.x * 256 + threadIdx.x;
  if (idx >= 512 * 512) return;
  int o = idx >> 9;        // output-feature index
  int c = idx & 511;       // input-feature index
  int og = o >> 7, oo = o & 127, cg = c >> 7, cc = c & 127;
  static const int   blkT[16] = {0,1,2,3, 1,0,3,2, 2,3,0,1, 3,2,1,0};
  static const float sgnT[16] = {1.f,-1.f,-1.f,-1.f, 1.f,1.f,1.f,-1.f,
                                 1.f,-1.f,1.f,1.f,   1.f,1.f,-1.f,1.f};
  int sel = og * 4 + cg;
  const float* Ws;
  switch (blkT[sel]) {
    case 0: Ws = wr; break;
    case 1: Ws = wi; break;
    case 2: Ws = wj; break;
    default: Ws = wk; break;
  }
  float v = sgnT[sel] * Ws[oo * 128 + cc];
  int kt = c >> 5, k = c & 31;
  int dst = kt * (OUT_F * BK) + o * BK + (k ^ ((o & 3) << 3));
  Bimg[dst] = f2bf(v);
}

// ---------------------------------------------------------------------------
// GEMM: out[M,512] = X[M,512] * W_eff^T (+bias)
// Block = 64 rows x ALL 512 cols: X enters exactly one CU exactly once
// (no nt-sibling amplification). BK=32, 16 steps, A+B double-buffered,
// 72KB LDS -> 2 blocks/CU, 16 waves/CU.
// ---------------------------------------------------------------------------
__global__ void __launch_bounds__(NTHREADS, 4)
quat_gemm_kernel(const float* __restrict__ X, const ushort* __restrict__ Bimg,
                 const float* __restrict__ bias, float* __restrict__ Out) {
  __shared__ __align__(16) ushort As[2][BM * BK];      // 2 x 4 KB
  __shared__ __align__(16) ushort Bs[2][OUT_F * BK];   // 2 x 32 KB

  int bid = blockIdx.x;
  size_t row0 = (size_t)bid * BM;

  int tid = threadIdx.x, lane = tid & 63, wid = tid >> 6;
  const int lrow = lane & 15;
  const int lg   = lane >> 4;
  const int wm = wid >> 2, wn = wid & 3;     // 2M x 4N wave grid

  const int ar = tid >> 3;                   // A row this thread loads [0,64)
  const int ac = (tid & 7) * 4;              // A col within BK [0,32) step 4

  float4 av;
  auto loadA = [&](int kt) {
    av = *reinterpret_cast<const float4*>(X + (row0 + ar) * KDIM + kt * BK + ac);
  };
  auto writeA = [&](ushort* Ab) {
    ushort4 o4;
    o4.x = f2bf(av.x); o4.y = f2bf(av.y); o4.z = f2bf(av.z); o4.w = f2bf(av.w);
    *reinterpret_cast<ushort4*>(Ab + ar * BK + (ac ^ ((ar & 3) << 3))) = o4;
  };
  auto stageB = [&](int kt, ushort* Bb) {
    const ushort* s = Bimg + kt * (OUT_F * BK) + (wid * 4) * 512 + lane * 8;
    ushort* d = Bb + (wid * 4) * 512;
#pragma unroll
    for (int i = 0; i < 4; ++i)
      gload_lds16(s + i * 512, d + i * 512);
  };

  floatx4 acc[2][8];
#pragma unroll
  for (int m = 0; m < 2; ++m)
#pragma unroll
    for (int n = 0; n < 8; ++n) acc[m][n] = {0.f, 0.f, 0.f, 0.f};

  // prologue: stage step 0 (A load first -> writeA's vmcnt leaves B in flight)
  loadA(0);
  stageB(0, Bs[0]);
  writeA(As[0]);
  __syncthreads();

#pragma unroll
  for (int kt = 0; kt < NSTEP; ++kt) {
    const int cur = kt & 1;
    if (kt < NSTEP - 1) {
      loadA(kt + 1);                    // oldest vmem: 1 float4 / thread
      stageB(kt + 1, Bs[cur ^ 1]);      // younger: 4 gload_lds / wave
    }

    // compute step kt
    short8 af[2];
#pragma unroll
    for (int m = 0; m < 2; ++m) {
      int row = wm * 32 + m * 16 + lrow;
      af[m] = *reinterpret_cast<const short8*>(
          &As[cur][row * BK + ((lg * 8) ^ ((row & 3) << 3))]);
    }
#pragma unroll
    for (int n = 0; n < 8; ++n) {
      int col = wn * 128 + n * 16 + lrow;
      short8 bf = *reinterpret_cast<const short8*>(
          &Bs[cur][col * BK + ((lg * 8) ^ ((col & 3) << 3))]);
      acc[0][n] = __builtin_amdgcn_mfma_f32_16x16x32_bf16(af[0], bf, acc[0][n], 0, 0, 0);
      acc[1][n] = __builtin_amdgcn_mfma_f32_16x16x32_bf16(af[1], bf, acc[1][n], 0, 0, 0);
    }

    if (kt < NSTEP - 1) writeA(As[cur ^ 1]);   // cvt + swizzled ds_write
    __syncthreads();
  }

  // epilogue: 64 x 512 fp32 tile
  float* Ob = Out + row0 * OUT_F;
#pragma unroll
  for (int n = 0; n < 8; ++n) {
    int col = wn * 128 + n * 16 + lrow;
    float bv = bias[col];
#pragma unroll
    for (int m = 0; m < 2; ++m) {
      int rbase = wm * 32 + m * 16 + lg * 4;
#pragma unroll
      for (int j = 0; j < 4; ++j)
        Ob[(size_t)(rbase + j) * OUT_F + col] = acc[m][n][j] + bv;
    }
  }
}

extern "C" void kernel_launch(void* const* d_in, const int* in_sizes, int n_in,
                              void* d_out, int out_size, void* d_ws, size_t ws_size,
                              hipStream_t stream) {
  const float* x    = (const float*)d_in[0];
  const float* wr   = (const float*)d_in[1];
  const float* wi   = (const float*)d_in[2];
  const float* wj   = (const float*)d_in[3];
  const float* wk   = (const float*)d_in[4];
  const float* bias = (const float*)d_in[5];
  float* out = (float*)d_out;
  ushort* Bimg = (ushort*)d_ws;         // 512 KB

  int M = in_sizes[0] / KDIM;           // 131072
  int nwg = M / BM;                     // 2048

  hipLaunchKernelGGL(quat_prep_kernel, dim3((512 * 512 + 255) / 256), dim3(256), 0, stream,
                     wr, wi, wj, wk, Bimg);
  hipLaunchKernelGGL(quat_gemm_kernel, dim3(nwg), dim3(NTHREADS), 0, stream,
                     x, Bimg, bias, out);
}

// Round 7
// 149.321 us; speedup vs baseline: 1.4648x; 1.0970x over previous
//
#include <hip/hip_runtime.h>
#include <hip/hip_bf16.h>
#include <stdint.h>

#define KDIM 512
#define OUT_F 512
#define BM 128           // rows per block
#define BK 64            // k per step
#define NSTEP 8          // KDIM / BK
#define NTHREADS 1024    // 16 waves, 4M x 4N

typedef __attribute__((ext_vector_type(8))) short short8;
typedef __attribute__((ext_vector_type(4))) float floatx4;

__device__ __forceinline__ ushort f2bf(float f) {
  uint32_t u = __builtin_bit_cast(uint32_t, f);
  uint32_t r = u + 0x7fffu + ((u >> 16) & 1u);   // RNE bf16
  return (ushort)(r >> 16);
}

typedef const __attribute__((address_space(1))) uint32_t* gas1_u32;
typedef __attribute__((address_space(3))) uint32_t* gas3_u32;

__device__ __forceinline__ void gload_lds16(const void* g, void* l) {
  __builtin_amdgcn_global_load_lds((gas1_u32)g, (gas3_u32)l, 16, 0, 0);
}

#define VMCNT2  asm volatile("s_waitcnt vmcnt(2)" ::: "memory")
#define VMCNT0  asm volatile("s_waitcnt vmcnt(0)" ::: "memory")
#define LGKM0   asm volatile("s_waitcnt lgkmcnt(0)" ::: "memory")
#define FENCE   __builtin_amdgcn_sched_barrier(0)
#define SBAR    __builtin_amdgcn_s_barrier()

// ---------------------------------------------------------------------------
// Prep: W_eff (512x512) bf16 as [kt(8)][o(512)][k(64)] with XOR swizzle baked
// in; GEMM stages each 64KB kt-slab linearly via global_load_lds, reads
// swizzled (G21: source perm == read perm, dest linear).
// ---------------------------------------------------------------------------
__global__ void quat_prep_kernel(const float* __restrict__ wr, const float* __restrict__ wi,
                                 const float* __restrict__ wj, const float* __restrict__ wk,
                                 ushort* __restrict__ Bimg) {
  int idx = blockIdx.x * 256 + threadIdx.x;
  if (idx >= 512 * 512) return;
  int o = idx >> 9;        // output-feature index
  int c = idx & 511;       // input-feature index
  int og = o >> 7, oo = o & 127, cg = c >> 7, cc = c & 127;
  static const int   blkT[16] = {0,1,2,3, 1,0,3,2, 2,3,0,1, 3,2,1,0};
  static const float sgnT[16] = {1.f,-1.f,-1.f,-1.f, 1.f,1.f,1.f,-1.f,
                                 1.f,-1.f,1.f,1.f,   1.f,1.f,-1.f,1.f};
  int sel = og * 4 + cg;
  const float* Ws;
  switch (blkT[sel]) {
    case 0: Ws = wr; break;
    case 1: Ws = wi; break;
    case 2: Ws = wj; break;
    default: Ws = wk; break;
  }
  float v = sgnT[sel] * Ws[oo * 128 + cc];
  int kt = c >> 6, k = c & 63;
  int dst = kt * (OUT_F * BK) + o * BK + (k ^ ((o & 7) << 3));
  Bimg[dst] = f2bf(v);
}

// ---------------------------------------------------------------------------
// GEMM: out[M,512] = X[M,512] * W_eff^T (+bias)
// Block = 128 rows x ALL 512 cols (X enters one CU once; B amplification
// halved vs BM=64). BK=64 -> 8 steps. Counted-vmcnt pipeline: B(t+1) staged
// during compute(t), A(t+2) reg-prefetched 2 deep; main loop never drains
// vmcnt to 0 (except last stage). LDS 160KB, 16 waves/CU.
// ---------------------------------------------------------------------------
__global__ void __launch_bounds__(NTHREADS, 4)
quat_gemm_kernel(const float* __restrict__ X, const ushort* __restrict__ Bimg,
                 const float* __restrict__ bias, float* __restrict__ Out) {
  __shared__ __align__(16) ushort As[2][BM * BK];      // 2 x 16 KB
  __shared__ __align__(16) ushort Bs[2][OUT_F * BK];   // 2 x 64 KB

  const int bid = blockIdx.x;
  const size_t row0 = (size_t)bid * BM;
  const int tid = threadIdx.x, lane = tid & 63, wid = tid >> 6;
  const int lrow = lane & 15;
  const int lg   = lane >> 4;
  const int wm = wid >> 2, wn = wid & 3;     // 4M x 4N wave grid

  const int ar = tid >> 3;                   // A row [0,128)
  const int ac = (tid & 7) * 8;              // A col [0,64) step 8

  float4 av[2][2];                           // 2-deep A prefetch, 8 floats each

  auto issueA = [&](int t, int p) {
    const float* s = X + (row0 + ar) * KDIM + t * BK + ac;
    av[p][0] = *reinterpret_cast<const float4*>(s);
    av[p][1] = *reinterpret_cast<const float4*>(s + 4);
  };
  auto writeA = [&](int p, ushort* Ab) {
    short8 o;
    o[0] = (short)f2bf(av[p][0].x); o[1] = (short)f2bf(av[p][0].y);
    o[2] = (short)f2bf(av[p][0].z); o[3] = (short)f2bf(av[p][0].w);
    o[4] = (short)f2bf(av[p][1].x); o[5] = (short)f2bf(av[p][1].y);
    o[6] = (short)f2bf(av[p][1].z); o[7] = (short)f2bf(av[p][1].w);
    *reinterpret_cast<short8*>(Ab + ar * BK + (ac ^ ((ar & 7) << 3))) = o;
  };
  auto stageB = [&](int t, ushort* Bb) {     // 64KB: 16 waves x 4KB
    const ushort* s = Bimg + t * (OUT_F * BK) + wid * 2048 + lane * 8;
    ushort* d = Bb + wid * 2048;
#pragma unroll
    for (int i = 0; i < 4; ++i)
      gload_lds16(s + i * 512, d + i * 512);
  };

  floatx4 acc[2][8];
#pragma unroll
  for (int m = 0; m < 2; ++m)
#pragma unroll
    for (int n = 0; n < 8; ++n) acc[m][n] = {0.f, 0.f, 0.f, 0.f};

  auto compute = [&](const ushort* Ab, const ushort* Bb) {
#pragma unroll
    for (int kh = 0; kh < 2; ++kh) {
      const int kb = kh * 32 + lg * 8;
      short8 af[2];
#pragma unroll
      for (int m = 0; m < 2; ++m) {
        int row = wm * 32 + m * 16 + lrow;
        af[m] = *reinterpret_cast<const short8*>(Ab + row * BK + (kb ^ ((row & 7) << 3)));
      }
#pragma unroll
      for (int n = 0; n < 8; ++n) {
        int col = wn * 128 + n * 16 + lrow;
        short8 bf = *reinterpret_cast<const short8*>(Bb + col * BK + (kb ^ ((col & 7) << 3)));
        acc[0][n] = __builtin_amdgcn_mfma_f32_16x16x32_bf16(af[0], bf, acc[0][n], 0, 0, 0);
        acc[1][n] = __builtin_amdgcn_mfma_f32_16x16x32_bf16(af[1], bf, acc[1][n], 0, 0, 0);
      }
    }
  };

  // ---- prologue ----
  issueA(0, 0);
  stageB(0, Bs[0]);
  issueA(1, 1);
  writeA(0, As[0]);        // compiler inserts counted wait for A(0) regs
  VMCNT2; FENCE;           // B(0) in LDS; A(1) stays in flight
  LGKM0; SBAR;

  // ---- steady steps t = 0..5: stage B(t+1), prefetch A(t+2) ----
#define STEP_MAIN(T)                                        \
  {                                                         \
    stageB((T) + 1, Bs[((T) & 1) ^ 1]);                     \
    issueA((T) + 2, (T) & 1);                               \
    writeA(((T) + 1) & 1, (ushort*)As[((T) & 1) ^ 1]);      \
    compute(As[(T) & 1], Bs[(T) & 1]);                      \
    VMCNT2; FENCE;                                          \
    LGKM0; SBAR;                                            \
  }
  STEP_MAIN(0) STEP_MAIN(1) STEP_MAIN(2)
  STEP_MAIN(3) STEP_MAIN(4) STEP_MAIN(5)
#undef STEP_MAIN

  // t = 6: stage B(7), no A(8)
  {
    stageB(7, Bs[1]);
    writeA(1, (ushort*)As[1]);
    compute(As[0], Bs[0]);
    VMCNT0; FENCE;
    LGKM0; SBAR;
  }
  // t = 7: compute only
  compute(As[1], Bs[1]);

  // ---- epilogue: 128x512 fp32 tile ----
  float* Ob = Out + row0 * OUT_F;
#pragma unroll
  for (int n = 0; n < 8; ++n) {
    int col = wn * 128 + n * 16 + lrow;
    float bv = bias[col];
#pragma unroll
    for (int m = 0; m < 2; ++m) {
      int rbase = wm * 32 + m * 16 + lg * 4;
#pragma unroll
      for (int j = 0; j < 4; ++j)
        Ob[(size_t)(rbase + j) * OUT_F + col] = acc[m][n][j] + bv;
    }
  }
}

extern "C" void kernel_launch(void* const* d_in, const int* in_sizes, int n_in,
                              void* d_out, int out_size, void* d_ws, size_t ws_size,
                              hipStream_t stream) {
  const float* x    = (const float*)d_in[0];
  const float* wr   = (const float*)d_in[1];
  const float* wi   = (const float*)d_in[2];
  const float* wj   = (const float*)d_in[3];
  const float* wk   = (const float*)d_in[4];
  const float* bias = (const float*)d_in[5];
  float* out = (float*)d_out;
  ushort* Bimg = (ushort*)d_ws;         // 512 KB

  int M = in_sizes[0] / KDIM;           // 131072
  int nwg = M / BM;                     // 1024

  hipLaunchKernelGGL(quat_prep_kernel, dim3((512 * 512 + 255) / 256), dim3(256), 0, stream,
                     wr, wi, wj, wk, Bimg);
  hipLaunchKernelGGL(quat_gemm_kernel, dim3(nwg), dim3(NTHREADS), 0, stream,
                     x, Bimg, bias, out);
}